// Round 7
// baseline (216.430 us; speedup 1.0000x reference)
//
#include <hip/hip_runtime.h>

#define N_NODES 50000
#define N_EDGES 625000
#define DIM 128

typedef __bf16 bf16x8 __attribute__((ext_vector_type(8)));
typedef __bf16 bf16x4 __attribute__((ext_vector_type(4)));
typedef float f32x4 __attribute__((ext_vector_type(4)));

__device__ __forceinline__ float bflo(unsigned u) { return __uint_as_float(u << 16); }
__device__ __forceinline__ float bfhi(unsigned u) { return __uint_as_float(u & 0xffff0000u); }

// ===========================================================================
// K1: fused [GEMM1 | histogram]. Histogram block 0 also zeroes h row N_NODES
// (the "zero row" used by K4's branchless gather). (unchanged from R6)
// ===========================================================================
__global__ __launch_bounds__(256) void gemm1_hist_k(
    const float* __restrict__ A_f32,
    const float* __restrict__ W,
    const float* __restrict__ bias,
    __bf16* __restrict__ out_bf16,
    const int* __restrict__ dst,
    int* __restrict__ deg,
    int gemm_blocks)
{
    const int t = threadIdx.x;

    if ((int)blockIdx.x >= gemm_blocks) {
        if ((int)blockIdx.x == gemm_blocks && t < 16) {
            bf16x8 z = {};
            *(bf16x8*)&out_bf16[(size_t)N_NODES * DIM + t * 8] = z;
        }
        int idx = ((int)blockIdx.x - gemm_blocks) * 256 + t;
        if (idx < N_EDGES / 4) {
            int4 d4 = ((const int4*)dst)[idx];
            atomicAdd(&deg[d4.x], 1);
            atomicAdd(&deg[d4.y], 1);
            atomicAdd(&deg[d4.z], 1);
            atomicAdd(&deg[d4.w], 1);
        }
        return;
    }

    __shared__ __align__(16) __bf16 w_lds[128 * 136];   // 34.8 KB

    for (int i = t; i < 4096; i += 256) {
        float4 f = ((const float4*)W)[i];
        int n = i >> 5;
        int k = (i & 31) << 2;
        __bf16* p = &w_lds[n * 136 + k];
        p[0] = (__bf16)f.x; p[1] = (__bf16)f.y;
        p[2] = (__bf16)f.z; p[3] = (__bf16)f.w;
    }
    __syncthreads();

    const int wave = t >> 6;
    const int lane = t & 63;
    const int q = lane >> 4;
    const int mr = lane & 15;

    const int m0 = blockIdx.x * 64 + wave * 16;
    int arow = m0 + mr;
    if (arow >= N_NODES) arow = N_NODES - 1;

    f32x4 acc[8] = {};

#pragma unroll
    for (int ks = 0; ks < 4; ++ks) {
        const int k0 = ks * 32 + q * 8;
        const float4* ap = (const float4*)&A_f32[(size_t)arow * DIM + k0];
        float4 a0 = ap[0], a1 = ap[1];
        bf16x8 af;
        af[0] = (__bf16)a0.x; af[1] = (__bf16)a0.y;
        af[2] = (__bf16)a0.z; af[3] = (__bf16)a0.w;
        af[4] = (__bf16)a1.x; af[5] = (__bf16)a1.y;
        af[6] = (__bf16)a1.z; af[7] = (__bf16)a1.w;
#pragma unroll
        for (int nt = 0; nt < 8; ++nt) {
            bf16x8 bfr = *(const bf16x8*)&w_lds[(nt * 16 + mr) * 136 + k0];
            acc[nt] = __builtin_amdgcn_mfma_f32_16x16x32_bf16(af, bfr, acc[nt], 0, 0, 0);
        }
    }

    __syncthreads();
    float* lds_f = (float*)w_lds;          // 64 x 132 fp32
#pragma unroll
    for (int nt = 0; nt < 8; ++nt)
#pragma unroll
        for (int r = 0; r < 4; ++r)
            lds_f[(wave * 16 + q * 4 + r) * 132 + nt * 16 + mr] = acc[nt][r];
    __syncthreads();

    const int nb = blockIdx.x * 64;
    for (int i = t; i < 2048; i += 256) {
        int lr = i >> 5;
        int cg = (i & 31) << 2;
        int grow = nb + lr;
        if (grow >= N_NODES) continue;
        float4 v = *(const float4*)&lds_f[lr * 132 + cg];
        float4 b4 = *(const float4*)&bias[cg];
        bf16x4 o;
        o[0] = (__bf16)fmaxf(v.x + b4.x, 0.f);
        o[1] = (__bf16)fmaxf(v.y + b4.y, 0.f);
        o[2] = (__bf16)fmaxf(v.z + b4.z, 0.f);
        o[3] = (__bf16)fmaxf(v.w + b4.w, 0.f);
        *(bf16x4*)&out_bf16[(size_t)grow * DIM + cg] = o;
    }
}

// ===========================================================================
// K2a/K2b: two-step exclusive scan (proven R2/R5 version).
// ===========================================================================
__global__ __launch_bounds__(256) void scan_blocks_k(
    int* __restrict__ deg, int* __restrict__ blocksums)
{
    __shared__ int s[256];
    const int t = threadIdx.x;
    const int base = blockIdx.x * 1024 + t * 4;

    int v[4] = {0, 0, 0, 0};
    if (base + 3 < N_NODES) {
        int4 qd = *(const int4*)&deg[base];
        v[0] = qd.x; v[1] = qd.y; v[2] = qd.z; v[3] = qd.w;
    } else {
#pragma unroll
        for (int j = 0; j < 4; ++j)
            if (base + j < N_NODES) v[j] = deg[base + j];
    }
    int sum = v[0] + v[1] + v[2] + v[3];
    s[t] = sum;
    __syncthreads();
    for (int off = 1; off < 256; off <<= 1) {
        int x = (t >= off) ? s[t - off] : 0;
        __syncthreads();
        s[t] += x;
        __syncthreads();
    }
    if (t == 255) blocksums[blockIdx.x] = s[255];
    int run = s[t] - sum;
#pragma unroll
    for (int j = 0; j < 4; ++j) {
        int ex = run;
        run += v[j];
        if (base + j < N_NODES) deg[base + j] = ex;
    }
}

__global__ __launch_bounds__(256) void scan_add_k(
    int* __restrict__ deg, const int* __restrict__ blocksums, int nblocks)
{
    __shared__ int carry_s;
    const int t = threadIdx.x;
    if (t < 64) {
        int v = (t < blockIdx.x && t < nblocks) ? blocksums[t] : 0;
#pragma unroll
        for (int off = 32; off > 0; off >>= 1) v += __shfl_down(v, off, 64);
        if (t == 0) carry_s = v;
    }
    __syncthreads();
    const int carry = carry_s;
    if (carry == 0) return;
    const int base = blockIdx.x * 1024 + t * 4;
#pragma unroll
    for (int j = 0; j < 4; ++j)
        if (base + j < N_NODES) deg[base + j] += carry;
}

// ===========================================================================
// K3: CSR fill, 4 edges/thread. After this, deg[d] = END offset of segment d.
// ===========================================================================
__global__ __launch_bounds__(256) void fill_k(
    const int* __restrict__ src, const int* __restrict__ dst,
    int* __restrict__ deg, int* __restrict__ edge_src)
{
    int idx = blockIdx.x * 256 + threadIdx.x;
    if (idx < N_EDGES / 4) {
        int4 s4 = ((const int4*)src)[idx];
        int4 d4 = ((const int4*)dst)[idx];
        edge_src[atomicAdd(&deg[d4.x], 1)] = s4.x;
        edge_src[atomicAdd(&deg[d4.y], 1)] = s4.y;
        edge_src[atomicAdd(&deg[d4.z], 1)] = s4.z;
        edge_src[atomicAdd(&deg[d4.w], 1)] = s4.w;
    }
}

// ===========================================================================
// K4: fused [aggregate + GIN combine + GEMM2 + bias + relu].
// R7: 2 waves per 16-row MFMA group (block covers 32 rows, grid 1563).
// Waves A/B each aggregate alternate 4-edge chunks (stride 8); B publishes
// its partial agg via padded LDS (stride 34 floats -> 2-way aliasing, free);
// A combines, adds the self term, runs the MFMAs. Doubles aggregation TLP
// (3125 -> 6250 waves) AND halves each wave's serial edge chain — the two
// factors the R6 counters said were the limit (occupancy 14.5%, VALU 14%).
// ===========================================================================
__global__ __launch_bounds__(256) void gemm2_agg_k(
    const __bf16* __restrict__ h,
    const int* __restrict__ deg,
    const int* __restrict__ edge_src,
    const float* __restrict__ eps_p,
    const float* __restrict__ W,
    const float* __restrict__ bias,
    float* __restrict__ out)
{
    __shared__ __align__(16) __bf16 w_lds[128 * 136];   // 34.8 KB
    __shared__ __align__(16) float comb[2][64][34];     // 17.4 KB, padded

    const int t = threadIdx.x;

    for (int i = t; i < 4096; i += 256) {
        float4 f = ((const float4*)W)[i];
        int n = i >> 5;
        int k = (i & 31) << 2;
        __bf16* p = &w_lds[n * 136 + k];
        p[0] = (__bf16)f.x; p[1] = (__bf16)f.y;
        p[2] = (__bf16)f.z; p[3] = (__bf16)f.w;
    }
    __syncthreads();

    const int wave = t >> 6;
    const int lane = t & 63;
    const int q = lane >> 4;
    const int mr = lane & 15;
    const int pair = wave >> 1;        // 0,1: which 16-row group
    const int sub  = wave & 1;         // 0 = wave A, 1 = wave B

    const int m0 = blockIdx.x * 32 + pair * 16;
    int arow = m0 + mr;
    if (arow >= N_NODES) arow = N_NODES - 1;

    const int start = arow ? deg[arow - 1] : 0;
    const int end   = deg[arow];

    float agg[4][8] = {};
    const int ZROW = N_NODES;          // zero row (written by K1)

    int ei = start + sub * 4;
    while (__any(ei < end)) {
        int sidx[4];
#pragma unroll
        for (int u = 0; u < 4; ++u) {
            bool pu = (ei + u) < end;
            int eidx = pu ? (ei + u) : 0;
            int sv = edge_src[eidx];
            sidx[u] = pu ? sv : ZROW;
        }
        uint4 r[8];
#pragma unroll
        for (int ks = 0; ks < 4; ++ks) {
            r[ks]     = *(const uint4*)&h[(size_t)sidx[0] * DIM + ks * 32 + q * 8];
            r[4 + ks] = *(const uint4*)&h[(size_t)sidx[1] * DIM + ks * 32 + q * 8];
        }
#pragma unroll
        for (int u = 0; u < 2; ++u)
#pragma unroll
            for (int ks = 0; ks < 4; ++ks) {
                uint4 rv = r[u * 4 + ks];
                agg[ks][0] += bflo(rv.x); agg[ks][1] += bfhi(rv.x);
                agg[ks][2] += bflo(rv.y); agg[ks][3] += bfhi(rv.y);
                agg[ks][4] += bflo(rv.z); agg[ks][5] += bfhi(rv.z);
                agg[ks][6] += bflo(rv.w); agg[ks][7] += bfhi(rv.w);
            }
#pragma unroll
        for (int ks = 0; ks < 4; ++ks) {
            r[ks]     = *(const uint4*)&h[(size_t)sidx[2] * DIM + ks * 32 + q * 8];
            r[4 + ks] = *(const uint4*)&h[(size_t)sidx[3] * DIM + ks * 32 + q * 8];
        }
#pragma unroll
        for (int u = 0; u < 2; ++u)
#pragma unroll
            for (int ks = 0; ks < 4; ++ks) {
                uint4 rv = r[u * 4 + ks];
                agg[ks][0] += bflo(rv.x); agg[ks][1] += bfhi(rv.x);
                agg[ks][2] += bflo(rv.y); agg[ks][3] += bfhi(rv.y);
                agg[ks][4] += bflo(rv.z); agg[ks][5] += bfhi(rv.z);
                agg[ks][6] += bflo(rv.w); agg[ks][7] += bfhi(rv.w);
            }
        ei += 8;
    }

    // Wave B publishes its partial aggregate
    if (sub == 1) {
        float* cp = &comb[pair][lane][0];
#pragma unroll
        for (int ks = 0; ks < 4; ++ks)
#pragma unroll
            for (int j = 0; j < 8; ++j)
                cp[ks * 8 + j] = agg[ks][j];
    }
    __syncthreads();

    f32x4 acc[8] = {};
    if (sub == 0) {
        const float* cp = &comb[pair][lane][0];
#pragma unroll
        for (int ks = 0; ks < 4; ++ks)
#pragma unroll
            for (int j = 0; j < 8; ++j)
                agg[ks][j] += cp[ks * 8 + j];

        const float eps = eps_p[0];
#pragma unroll
        for (int ks = 0; ks < 4; ++ks) {
            const int k0 = ks * 32 + q * 8;
            uint4 hraw = *(const uint4*)&h[(size_t)arow * DIM + k0];
            float hf[8] = { bflo(hraw.x), bfhi(hraw.x), bflo(hraw.y), bfhi(hraw.y),
                            bflo(hraw.z), bfhi(hraw.z), bflo(hraw.w), bfhi(hraw.w) };
            bf16x8 af;
#pragma unroll
            for (int j = 0; j < 8; ++j)
                af[j] = (__bf16)(1.0f + eps * hf[j] + agg[ks][j]);
#pragma unroll
            for (int nt = 0; nt < 8; ++nt) {
                bf16x8 bfr = *(const bf16x8*)&w_lds[(nt * 16 + mr) * 136 + k0];
                acc[nt] = __builtin_amdgcn_mfma_f32_16x16x32_bf16(af, bfr, acc[nt], 0, 0, 0);
            }
        }
    }

    __syncthreads();                       // all reads of w_lds/comb done
    float* lds_f = (float*)w_lds;          // 32 rows x 132 fp32 (16.9 KB)
    if (sub == 0) {
#pragma unroll
        for (int nt = 0; nt < 8; ++nt)
#pragma unroll
            for (int r2 = 0; r2 < 4; ++r2)
                lds_f[(pair * 16 + q * 4 + r2) * 132 + nt * 16 + mr] = acc[nt][r2];
    }
    __syncthreads();

    const int nb = blockIdx.x * 32;
    for (int i = t; i < 1024; i += 256) {
        int lr = i >> 5;
        int cg = (i & 31) << 2;
        int grow = nb + lr;
        if (grow >= N_NODES) continue;
        float4 v = *(const float4*)&lds_f[lr * 132 + cg];
        float4 b4 = *(const float4*)&bias[cg];
        v.x = fmaxf(v.x + b4.x, 0.f);
        v.y = fmaxf(v.y + b4.y, 0.f);
        v.z = fmaxf(v.z + b4.z, 0.f);
        v.w = fmaxf(v.w + b4.w, 0.f);
        *(float4*)&out[(size_t)grow * DIM + cg] = v;
    }
}

extern "C" void kernel_launch(void* const* d_in, const int* in_sizes, int n_in,
                              void* d_out, int out_size, void* d_ws, size_t ws_size,
                              hipStream_t stream) {
    const float* feats = (const float*)d_in[0];
    const int*   src   = (const int*)d_in[1];
    const int*   dst   = (const int*)d_in[2];
    const float* W_f   = (const float*)d_in[3];
    const float* b_f   = (const float*)d_in[4];
    const float* W_phy = (const float*)d_in[5];
    const float* b_phy = (const float*)d_in[6];
    const float* eps   = (const float*)d_in[7];
    float* out = (float*)d_out;

    const size_t HN = (size_t)(N_NODES + 1) * DIM;      // +1 zero row
    __bf16* h     = (__bf16*)d_ws;                      // 12.8 MB
    int* edge_src = (int*)(h + HN);                     // 2.5 MB
    int* deg      = edge_src + N_EDGES;                 // 200 KB
    int* blocksums = deg + N_NODES;                     // 196 B

    const int gblocks = (N_NODES + 63) / 64;            // 782  (K1 gemm part)
    const int g2blocks = (N_NODES + 31) / 32;           // 1563 (K4)
    const int hblocks = (N_EDGES / 4 + 255) / 256;      // 611
    const int nscan = (N_NODES + 1023) / 1024;          // 49

    hipMemsetAsync(deg, 0, N_NODES * sizeof(int), stream);

    gemm1_hist_k<<<gblocks + hblocks, 256, 0, stream>>>(
        feats, W_f, b_f, h, dst, deg, gblocks);

    scan_blocks_k<<<nscan, 256, 0, stream>>>(deg, blocksums);
    scan_add_k<<<nscan, 256, 0, stream>>>(deg, blocksums, nscan);

    fill_k<<<hblocks, 256, 0, stream>>>(src, dst, deg, edge_src);

    gemm2_agg_k<<<g2blocks, 256, 0, stream>>>(
        h, deg, edge_src, eps, W_phy, b_phy, out);
}

// Round 8
// 182.711 us; speedup vs baseline: 1.1845x; 1.1845x over previous
//
#include <hip/hip_runtime.h>

#define N_NODES 50000
#define N_EDGES 625000
#define DIM 128
#define CAP 64            // bucket capacity per node; max degree ~29 (Poisson 12.5)

typedef __bf16 bf16x8 __attribute__((ext_vector_type(8)));
typedef __bf16 bf16x4 __attribute__((ext_vector_type(4)));
typedef float f32x4 __attribute__((ext_vector_type(4)));

__device__ __forceinline__ float bflo(unsigned u) { return __uint_as_float(u << 16); }
__device__ __forceinline__ float bfhi(unsigned u) { return __uint_as_float(u & 0xffff0000u); }

// ===========================================================================
// K1: fused [GEMM1 | bucket-CSR fill].
// Blocks [0, gemm_blocks): h[i][:] = relu(feats[i] @ W_f^T + b_f) as bf16.
// Blocks [gemm_blocks, ...): pos = atomicAdd(&cnt[dst],1);
//                            bucket[dst*CAP+pos] = src.   (no hist, no scan)
// First fill block also zeroes h row N_NODES (K4's branchless-gather target).
// ===========================================================================
__global__ __launch_bounds__(256) void gemm1_fill_k(
    const float* __restrict__ A_f32,
    const float* __restrict__ W,
    const float* __restrict__ bias,
    __bf16* __restrict__ out_bf16,
    const int* __restrict__ src,
    const int* __restrict__ dst,
    int* __restrict__ cnt,
    int* __restrict__ bucket,
    int gemm_blocks)
{
    const int t = threadIdx.x;

    if ((int)blockIdx.x >= gemm_blocks) {
        if ((int)blockIdx.x == gemm_blocks && t < 16) {
            bf16x8 z = {};
            *(bf16x8*)&out_bf16[(size_t)N_NODES * DIM + t * 8] = z;
        }
        int idx = ((int)blockIdx.x - gemm_blocks) * 256 + t;
        if (idx < N_EDGES / 4) {
            int4 s4 = ((const int4*)src)[idx];
            int4 d4 = ((const int4*)dst)[idx];
            int p0 = atomicAdd(&cnt[d4.x], 1);
            bucket[(d4.x << 6) + p0] = s4.x;
            int p1 = atomicAdd(&cnt[d4.y], 1);
            bucket[(d4.y << 6) + p1] = s4.y;
            int p2 = atomicAdd(&cnt[d4.z], 1);
            bucket[(d4.z << 6) + p2] = s4.z;
            int p3 = atomicAdd(&cnt[d4.w], 1);
            bucket[(d4.w << 6) + p3] = s4.w;
        }
        return;
    }

    // ---- GEMM1 path (R3-proven MFMA structure) ----
    __shared__ __align__(16) __bf16 w_lds[128 * 136];   // 34.8 KB

    for (int i = t; i < 4096; i += 256) {
        float4 f = ((const float4*)W)[i];
        int n = i >> 5;
        int k = (i & 31) << 2;
        __bf16* p = &w_lds[n * 136 + k];
        p[0] = (__bf16)f.x; p[1] = (__bf16)f.y;
        p[2] = (__bf16)f.z; p[3] = (__bf16)f.w;
    }
    __syncthreads();

    const int wave = t >> 6;
    const int lane = t & 63;
    const int q = lane >> 4;
    const int mr = lane & 15;

    const int m0 = blockIdx.x * 64 + wave * 16;
    int arow = m0 + mr;
    if (arow >= N_NODES) arow = N_NODES - 1;

    f32x4 acc[8] = {};

#pragma unroll
    for (int ks = 0; ks < 4; ++ks) {
        const int k0 = ks * 32 + q * 8;
        const float4* ap = (const float4*)&A_f32[(size_t)arow * DIM + k0];
        float4 a0 = ap[0], a1 = ap[1];
        bf16x8 af;
        af[0] = (__bf16)a0.x; af[1] = (__bf16)a0.y;
        af[2] = (__bf16)a0.z; af[3] = (__bf16)a0.w;
        af[4] = (__bf16)a1.x; af[5] = (__bf16)a1.y;
        af[6] = (__bf16)a1.z; af[7] = (__bf16)a1.w;
#pragma unroll
        for (int nt = 0; nt < 8; ++nt) {
            bf16x8 bfr = *(const bf16x8*)&w_lds[(nt * 16 + mr) * 136 + k0];
            acc[nt] = __builtin_amdgcn_mfma_f32_16x16x32_bf16(af, bfr, acc[nt], 0, 0, 0);
        }
    }

    __syncthreads();
    float* lds_f = (float*)w_lds;          // 64 x 132 fp32
#pragma unroll
    for (int nt = 0; nt < 8; ++nt)
#pragma unroll
        for (int r = 0; r < 4; ++r)
            lds_f[(wave * 16 + q * 4 + r) * 132 + nt * 16 + mr] = acc[nt][r];
    __syncthreads();

    const int nb = blockIdx.x * 64;
    for (int i = t; i < 2048; i += 256) {
        int lr = i >> 5;
        int cg = (i & 31) << 2;
        int grow = nb + lr;
        if (grow >= N_NODES) continue;
        float4 v = *(const float4*)&lds_f[lr * 132 + cg];
        float4 b4 = *(const float4*)&bias[cg];
        bf16x4 o;
        o[0] = (__bf16)fmaxf(v.x + b4.x, 0.f);
        o[1] = (__bf16)fmaxf(v.y + b4.y, 0.f);
        o[2] = (__bf16)fmaxf(v.z + b4.z, 0.f);
        o[3] = (__bf16)fmaxf(v.w + b4.w, 0.f);
        *(bf16x4*)&out_bf16[(size_t)grow * DIM + cg] = o;
    }
}

// ===========================================================================
// K2: fused [aggregate + GIN combine + GEMM2 + bias + relu].
// R6-proven body (one wave per 16 rows, branchless 4-edge unroll); bucket
// CSR: start = arow*CAP (no dependent deg[arow-1] load), end = start + cnt.
// Out-of-range edges read zero row h[N_NODES] (uniform addr -> broadcast).
// ===========================================================================
__global__ __launch_bounds__(256) void gemm2_agg_k(
    const __bf16* __restrict__ h,
    const int* __restrict__ cnt,
    const int* __restrict__ bucket,
    const float* __restrict__ eps_p,
    const float* __restrict__ W,
    const float* __restrict__ bias,
    float* __restrict__ out)
{
    __shared__ __align__(16) __bf16 w_lds[128 * 136];   // 34.8 KB

    const int t = threadIdx.x;

    for (int i = t; i < 4096; i += 256) {
        float4 f = ((const float4*)W)[i];
        int n = i >> 5;
        int k = (i & 31) << 2;
        __bf16* p = &w_lds[n * 136 + k];
        p[0] = (__bf16)f.x; p[1] = (__bf16)f.y;
        p[2] = (__bf16)f.z; p[3] = (__bf16)f.w;
    }
    __syncthreads();

    const int wave = t >> 6;
    const int lane = t & 63;
    const int q = lane >> 4;
    const int mr = lane & 15;

    const int m0 = blockIdx.x * 64 + wave * 16;
    int arow = m0 + mr;
    if (arow >= N_NODES) arow = N_NODES - 1;

    const int start = arow << 6;           // bucket base (CAP=64)
    const int end   = start + cnt[arow];

    float agg[4][8] = {};
    const int ZROW = N_NODES;              // zero row (written by K1)

    int ei = start;
    while (__any(ei < end)) {
        int sidx[4];
#pragma unroll
        for (int u = 0; u < 4; ++u) {
            bool pu = (ei + u) < end;
            int eidx = pu ? (ei + u) : start;
            int sv = bucket[eidx];
            sidx[u] = pu ? sv : ZROW;
        }
        uint4 r[8];
#pragma unroll
        for (int ks = 0; ks < 4; ++ks) {
            r[ks]     = *(const uint4*)&h[(size_t)sidx[0] * DIM + ks * 32 + q * 8];
            r[4 + ks] = *(const uint4*)&h[(size_t)sidx[1] * DIM + ks * 32 + q * 8];
        }
#pragma unroll
        for (int u = 0; u < 2; ++u)
#pragma unroll
            for (int ks = 0; ks < 4; ++ks) {
                uint4 rv = r[u * 4 + ks];
                agg[ks][0] += bflo(rv.x); agg[ks][1] += bfhi(rv.x);
                agg[ks][2] += bflo(rv.y); agg[ks][3] += bfhi(rv.y);
                agg[ks][4] += bflo(rv.z); agg[ks][5] += bfhi(rv.z);
                agg[ks][6] += bflo(rv.w); agg[ks][7] += bfhi(rv.w);
            }
#pragma unroll
        for (int ks = 0; ks < 4; ++ks) {
            r[ks]     = *(const uint4*)&h[(size_t)sidx[2] * DIM + ks * 32 + q * 8];
            r[4 + ks] = *(const uint4*)&h[(size_t)sidx[3] * DIM + ks * 32 + q * 8];
        }
#pragma unroll
        for (int u = 0; u < 2; ++u)
#pragma unroll
            for (int ks = 0; ks < 4; ++ks) {
                uint4 rv = r[u * 4 + ks];
                agg[ks][0] += bflo(rv.x); agg[ks][1] += bfhi(rv.x);
                agg[ks][2] += bflo(rv.y); agg[ks][3] += bfhi(rv.y);
                agg[ks][4] += bflo(rv.z); agg[ks][5] += bfhi(rv.z);
                agg[ks][6] += bflo(rv.w); agg[ks][7] += bfhi(rv.w);
            }
        ei += 4;
    }

    const float eps = eps_p[0];
    f32x4 acc[8] = {};

#pragma unroll
    for (int ks = 0; ks < 4; ++ks) {
        const int k0 = ks * 32 + q * 8;
        uint4 hraw = *(const uint4*)&h[(size_t)arow * DIM + k0];
        float hf[8] = { bflo(hraw.x), bfhi(hraw.x), bflo(hraw.y), bfhi(hraw.y),
                        bflo(hraw.z), bfhi(hraw.z), bflo(hraw.w), bfhi(hraw.w) };
        bf16x8 af;
#pragma unroll
        for (int j = 0; j < 8; ++j)
            af[j] = (__bf16)(1.0f + eps * hf[j] + agg[ks][j]);
#pragma unroll
        for (int nt = 0; nt < 8; ++nt) {
            bf16x8 bfr = *(const bf16x8*)&w_lds[(nt * 16 + mr) * 136 + k0];
            acc[nt] = __builtin_amdgcn_mfma_f32_16x16x32_bf16(af, bfr, acc[nt], 0, 0, 0);
        }
    }

    __syncthreads();
    float* lds_f = (float*)w_lds;
#pragma unroll
    for (int nt = 0; nt < 8; ++nt)
#pragma unroll
        for (int r2 = 0; r2 < 4; ++r2)
            lds_f[(wave * 16 + q * 4 + r2) * 132 + nt * 16 + mr] = acc[nt][r2];
    __syncthreads();

    const int nb = blockIdx.x * 64;
    for (int i = t; i < 2048; i += 256) {
        int lr = i >> 5;
        int cg = (i & 31) << 2;
        int grow = nb + lr;
        if (grow >= N_NODES) continue;
        float4 v = *(const float4*)&lds_f[lr * 132 + cg];
        float4 b4 = *(const float4*)&bias[cg];
        v.x = fmaxf(v.x + b4.x, 0.f);
        v.y = fmaxf(v.y + b4.y, 0.f);
        v.z = fmaxf(v.z + b4.z, 0.f);
        v.w = fmaxf(v.w + b4.w, 0.f);
        *(float4*)&out[(size_t)grow * DIM + cg] = v;
    }
}

extern "C" void kernel_launch(void* const* d_in, const int* in_sizes, int n_in,
                              void* d_out, int out_size, void* d_ws, size_t ws_size,
                              hipStream_t stream) {
    const float* feats = (const float*)d_in[0];
    const int*   src   = (const int*)d_in[1];
    const int*   dst   = (const int*)d_in[2];
    const float* W_f   = (const float*)d_in[3];
    const float* b_f   = (const float*)d_in[4];
    const float* W_phy = (const float*)d_in[5];
    const float* b_phy = (const float*)d_in[6];
    const float* eps   = (const float*)d_in[7];
    float* out = (float*)d_out;

    const size_t HN = (size_t)(N_NODES + 1) * DIM;      // +1 zero row
    __bf16* h   = (__bf16*)d_ws;                        // 12.8 MB
    int* bucket = (int*)(h + HN);                       // 50000*64*4 = 12.8 MB
    int* cnt    = bucket + (size_t)N_NODES * CAP;       // 200 KB

    const int gblocks = (N_NODES + 63) / 64;            // 782
    const int fblocks = (N_EDGES / 4 + 255) / 256;      // 611

    hipMemsetAsync(cnt, 0, N_NODES * sizeof(int), stream);

    gemm1_fill_k<<<gblocks + fblocks, 256, 0, stream>>>(
        feats, W_f, b_f, h, src, dst, cnt, bucket, gblocks);

    gemm2_agg_k<<<gblocks, 256, 0, stream>>>(
        h, cnt, bucket, eps, W_phy, b_phy, out);
}

// Round 9
// 165.979 us; speedup vs baseline: 1.3040x; 1.1008x over previous
//
#include <hip/hip_runtime.h>

#define N_NODES 50000
#define N_EDGES 625000
#define DIM 128
#define CAP 64            // bucket capacity per node; max degree ~29 (Poisson 12.5)

typedef __bf16 bf16x8 __attribute__((ext_vector_type(8)));
typedef __bf16 bf16x4 __attribute__((ext_vector_type(4)));
typedef __bf16 bf16x2 __attribute__((ext_vector_type(2)));
typedef float f32x4 __attribute__((ext_vector_type(4)));

__device__ __forceinline__ float bflo(unsigned u) { return __uint_as_float(u << 16); }
__device__ __forceinline__ float bfhi(unsigned u) { return __uint_as_float(u & 0xffff0000u); }

// ===========================================================================
// K1: fused [GEMM1 | bucket-CSR fill].  (unchanged from R8)
// Blocks [0, gemm_blocks): h[i][:] = relu(feats[i] @ W_f^T + b_f) as bf16.
// Blocks [gemm_blocks, ...): pos = atomicAdd(&cnt[dst],1);
//                            bucket[dst*CAP+pos] = src.
// First fill block also zeroes h row N_NODES (branchless-gather target).
// ===========================================================================
__global__ __launch_bounds__(256) void gemm1_fill_k(
    const float* __restrict__ A_f32,
    const float* __restrict__ W,
    const float* __restrict__ bias,
    __bf16* __restrict__ out_bf16,
    const int* __restrict__ src,
    const int* __restrict__ dst,
    int* __restrict__ cnt,
    int* __restrict__ bucket,
    int gemm_blocks)
{
    const int t = threadIdx.x;

    if ((int)blockIdx.x >= gemm_blocks) {
        if ((int)blockIdx.x == gemm_blocks && t < 16) {
            bf16x8 z = {};
            *(bf16x8*)&out_bf16[(size_t)N_NODES * DIM + t * 8] = z;
        }
        int idx = ((int)blockIdx.x - gemm_blocks) * 256 + t;
        if (idx < N_EDGES / 4) {
            int4 s4 = ((const int4*)src)[idx];
            int4 d4 = ((const int4*)dst)[idx];
            int p0 = atomicAdd(&cnt[d4.x], 1);
            bucket[(d4.x << 6) + p0] = s4.x;
            int p1 = atomicAdd(&cnt[d4.y], 1);
            bucket[(d4.y << 6) + p1] = s4.y;
            int p2 = atomicAdd(&cnt[d4.z], 1);
            bucket[(d4.z << 6) + p2] = s4.z;
            int p3 = atomicAdd(&cnt[d4.w], 1);
            bucket[(d4.w << 6) + p3] = s4.w;
        }
        return;
    }

    __shared__ __align__(16) __bf16 w_lds[128 * 136];   // 34.8 KB

    for (int i = t; i < 4096; i += 256) {
        float4 f = ((const float4*)W)[i];
        int n = i >> 5;
        int k = (i & 31) << 2;
        __bf16* p = &w_lds[n * 136 + k];
        p[0] = (__bf16)f.x; p[1] = (__bf16)f.y;
        p[2] = (__bf16)f.z; p[3] = (__bf16)f.w;
    }
    __syncthreads();

    const int wave = t >> 6;
    const int lane = t & 63;
    const int q = lane >> 4;
    const int mr = lane & 15;

    const int m0 = blockIdx.x * 64 + wave * 16;
    int arow = m0 + mr;
    if (arow >= N_NODES) arow = N_NODES - 1;

    f32x4 acc[8] = {};

#pragma unroll
    for (int ks = 0; ks < 4; ++ks) {
        const int k0 = ks * 32 + q * 8;
        const float4* ap = (const float4*)&A_f32[(size_t)arow * DIM + k0];
        float4 a0 = ap[0], a1 = ap[1];
        bf16x8 af;
        af[0] = (__bf16)a0.x; af[1] = (__bf16)a0.y;
        af[2] = (__bf16)a0.z; af[3] = (__bf16)a0.w;
        af[4] = (__bf16)a1.x; af[5] = (__bf16)a1.y;
        af[6] = (__bf16)a1.z; af[7] = (__bf16)a1.w;
#pragma unroll
        for (int nt = 0; nt < 8; ++nt) {
            bf16x8 bfr = *(const bf16x8*)&w_lds[(nt * 16 + mr) * 136 + k0];
            acc[nt] = __builtin_amdgcn_mfma_f32_16x16x32_bf16(af, bfr, acc[nt], 0, 0, 0);
        }
    }

    __syncthreads();
    float* lds_f = (float*)w_lds;          // 64 x 132 fp32
#pragma unroll
    for (int nt = 0; nt < 8; ++nt)
#pragma unroll
        for (int r = 0; r < 4; ++r)
            lds_f[(wave * 16 + q * 4 + r) * 132 + nt * 16 + mr] = acc[nt][r];
    __syncthreads();

    const int nb = blockIdx.x * 64;
    for (int i = t; i < 2048; i += 256) {
        int lr = i >> 5;
        int cg = (i & 31) << 2;
        int grow = nb + lr;
        if (grow >= N_NODES) continue;
        float4 v = *(const float4*)&lds_f[lr * 132 + cg];
        float4 b4 = *(const float4*)&bias[cg];
        bf16x4 o;
        o[0] = (__bf16)fmaxf(v.x + b4.x, 0.f);
        o[1] = (__bf16)fmaxf(v.y + b4.y, 0.f);
        o[2] = (__bf16)fmaxf(v.z + b4.z, 0.f);
        o[3] = (__bf16)fmaxf(v.w + b4.w, 0.f);
        *(bf16x4*)&out_bf16[(size_t)grow * DIM + cg] = o;
    }
}

// ===========================================================================
// K2: aggregate + GIN combine, DE-FUSED from the GEMM for max TLP.
// One full wave per node (50000 waves, 16x the fused version's TLP). Each
// lane owns 2 channels (uint = 2 bf16). Per edge, the wave reads one 256 B
// h row fully coalesced. 4-edge unroll, branchless via zero row h[N_NODES].
// Writes c = bf16(1 + eps*h_self + sum_neigh h) — the exact value the fused
// kernel fed the MFMA, so numerics are unchanged.
// ===========================================================================
__global__ __launch_bounds__(256) void agg_combine_k(
    const __bf16* __restrict__ h,
    const int* __restrict__ cnt,
    const int* __restrict__ bucket,
    const float* __restrict__ eps_p,
    __bf16* __restrict__ c)
{
    const int t = threadIdx.x;
    const int node = blockIdx.x * 4 + (t >> 6);   // grid 12500 x 4 = 50000
    const int lane = t & 63;
    const int ch = lane << 1;                     // channels ch, ch+1

    const int deg = cnt[node];
    const int base = node << 6;
    const int ZROW = N_NODES;

    float ax = 0.f, ay = 0.f;
    for (int e = 0; e < deg; e += 4) {
        uint4 i4 = *(const uint4*)&bucket[base + e];   // broadcast (uniform addr)
        int s0 = (int)i4.x;
        int s1 = (e + 1 < deg) ? (int)i4.y : ZROW;
        int s2 = (e + 2 < deg) ? (int)i4.z : ZROW;
        int s3 = (e + 3 < deg) ? (int)i4.w : ZROW;
        unsigned v0 = *(const unsigned*)&h[(size_t)s0 * DIM + ch];
        unsigned v1 = *(const unsigned*)&h[(size_t)s1 * DIM + ch];
        unsigned v2 = *(const unsigned*)&h[(size_t)s2 * DIM + ch];
        unsigned v3 = *(const unsigned*)&h[(size_t)s3 * DIM + ch];
        ax += bflo(v0) + bflo(v1) + bflo(v2) + bflo(v3);
        ay += bfhi(v0) + bfhi(v1) + bfhi(v2) + bfhi(v3);
    }

    const float eps = eps_p[0];
    unsigned sv = *(const unsigned*)&h[(size_t)node * DIM + ch];
    bf16x2 o;
    o[0] = (__bf16)(1.0f + eps * bflo(sv) + ax);
    o[1] = (__bf16)(1.0f + eps * bfhi(sv) + ay);
    *(bf16x2*)&c[(size_t)node * DIM + ch] = o;
}

// ===========================================================================
// K3: pure bf16 MFMA GEMM + bias + relu: out = relu(c @ W_phy^T + b_phy).
// Same proven structure as K1's gemm path; A is already bf16 (no convert).
// ===========================================================================
__global__ __launch_bounds__(256) void gemm2_k(
    const __bf16* __restrict__ A,
    const float* __restrict__ W,
    const float* __restrict__ bias,
    float* __restrict__ out)
{
    __shared__ __align__(16) __bf16 w_lds[128 * 136];   // 34.8 KB

    const int t = threadIdx.x;

    for (int i = t; i < 4096; i += 256) {
        float4 f = ((const float4*)W)[i];
        int n = i >> 5;
        int k = (i & 31) << 2;
        __bf16* p = &w_lds[n * 136 + k];
        p[0] = (__bf16)f.x; p[1] = (__bf16)f.y;
        p[2] = (__bf16)f.z; p[3] = (__bf16)f.w;
    }
    __syncthreads();

    const int wave = t >> 6;
    const int lane = t & 63;
    const int q = lane >> 4;
    const int mr = lane & 15;

    const int m0 = blockIdx.x * 64 + wave * 16;
    int arow = m0 + mr;
    if (arow >= N_NODES) arow = N_NODES - 1;

    f32x4 acc[8] = {};

#pragma unroll
    for (int ks = 0; ks < 4; ++ks) {
        const int k0 = ks * 32 + q * 8;
        bf16x8 af = *(const bf16x8*)&A[(size_t)arow * DIM + k0];
#pragma unroll
        for (int nt = 0; nt < 8; ++nt) {
            bf16x8 bfr = *(const bf16x8*)&w_lds[(nt * 16 + mr) * 136 + k0];
            acc[nt] = __builtin_amdgcn_mfma_f32_16x16x32_bf16(af, bfr, acc[nt], 0, 0, 0);
        }
    }

    __syncthreads();
    float* lds_f = (float*)w_lds;
#pragma unroll
    for (int nt = 0; nt < 8; ++nt)
#pragma unroll
        for (int r2 = 0; r2 < 4; ++r2)
            lds_f[(wave * 16 + q * 4 + r2) * 132 + nt * 16 + mr] = acc[nt][r2];
    __syncthreads();

    const int nb = blockIdx.x * 64;
    for (int i = t; i < 2048; i += 256) {
        int lr = i >> 5;
        int cg = (i & 31) << 2;
        int grow = nb + lr;
        if (grow >= N_NODES) continue;
        float4 v = *(const float4*)&lds_f[lr * 132 + cg];
        float4 b4 = *(const float4*)&bias[cg];
        v.x = fmaxf(v.x + b4.x, 0.f);
        v.y = fmaxf(v.y + b4.y, 0.f);
        v.z = fmaxf(v.z + b4.z, 0.f);
        v.w = fmaxf(v.w + b4.w, 0.f);
        *(float4*)&out[(size_t)grow * DIM + cg] = v;
    }
}

extern "C" void kernel_launch(void* const* d_in, const int* in_sizes, int n_in,
                              void* d_out, int out_size, void* d_ws, size_t ws_size,
                              hipStream_t stream) {
    const float* feats = (const float*)d_in[0];
    const int*   src   = (const int*)d_in[1];
    const int*   dst   = (const int*)d_in[2];
    const float* W_f   = (const float*)d_in[3];
    const float* b_f   = (const float*)d_in[4];
    const float* W_phy = (const float*)d_in[5];
    const float* b_phy = (const float*)d_in[6];
    const float* eps   = (const float*)d_in[7];
    float* out = (float*)d_out;

    const size_t HN = (size_t)(N_NODES + 1) * DIM;      // +1 zero row
    __bf16* h   = (__bf16*)d_ws;                        // 12.8 MB
    __bf16* c   = h + HN;                               // 12.8 MB (GEMM2 input)
    int* bucket = (int*)(c + (size_t)N_NODES * DIM);    // 12.8 MB
    int* cnt    = bucket + (size_t)N_NODES * CAP;       // 200 KB

    const int gblocks = (N_NODES + 63) / 64;            // 782
    const int fblocks = (N_EDGES / 4 + 255) / 256;      // 611

    hipMemsetAsync(cnt, 0, N_NODES * sizeof(int), stream);

    gemm1_fill_k<<<gblocks + fblocks, 256, 0, stream>>>(
        feats, W_f, b_f, h, src, dst, cnt, bucket, gblocks);

    agg_combine_k<<<N_NODES / 4, 256, 0, stream>>>(
        h, cnt, bucket, eps, c);

    gemm2_k<<<gblocks, 256, 0, stream>>>(
        c, W_phy, b_phy, out);
}

// Round 10
// 161.232 us; speedup vs baseline: 1.3424x; 1.0294x over previous
//
#include <hip/hip_runtime.h>

#define N_NODES 50000
#define N_EDGES 625000
#define DIM 128
#define CAP 64            // bucket capacity per node; max degree ~29 (Poisson 12.5)

typedef __bf16 bf16x8 __attribute__((ext_vector_type(8)));
typedef __bf16 bf16x4 __attribute__((ext_vector_type(4)));
typedef __bf16 bf16x2 __attribute__((ext_vector_type(2)));
typedef float f32x4 __attribute__((ext_vector_type(4)));

__device__ __forceinline__ float bflo(unsigned u) { return __uint_as_float(u << 16); }
__device__ __forceinline__ float bfhi(unsigned u) { return __uint_as_float(u & 0xffff0000u); }

// ===========================================================================
// K1: fused [GEMM1 | bucket-CSR fill], 512-thread blocks.
// GEMM: 128 rows/block (8 waves x 16 rows) — halves W re-staging vs R9;
// W staged with packed bf16x4 (ds_write_b64, was 4x scalar u16 stores).
// Epilogue: two 64-row passes through a reused 64x132 fp32 LDS buffer.
// Fill blocks: pos = atomicAdd(&cnt[dst],1); bucket[dst*CAP+pos] = src.
// ===========================================================================
__global__ __launch_bounds__(512) void gemm1_fill_k(
    const float* __restrict__ A_f32,
    const float* __restrict__ W,
    const float* __restrict__ bias,
    __bf16* __restrict__ out_bf16,
    const int* __restrict__ src,
    const int* __restrict__ dst,
    int* __restrict__ cnt,
    int* __restrict__ bucket,
    int gemm_blocks)
{
    const int t = threadIdx.x;

    if ((int)blockIdx.x >= gemm_blocks) {
        if ((int)blockIdx.x == gemm_blocks && t < 16) {
            bf16x8 z = {};
            *(bf16x8*)&out_bf16[(size_t)N_NODES * DIM + t * 8] = z;
        }
        int idx = ((int)blockIdx.x - gemm_blocks) * 512 + t;
        if (idx < N_EDGES / 4) {
            int4 s4 = ((const int4*)src)[idx];
            int4 d4 = ((const int4*)dst)[idx];
            int p0 = atomicAdd(&cnt[d4.x], 1);
            bucket[(d4.x << 6) + p0] = s4.x;
            int p1 = atomicAdd(&cnt[d4.y], 1);
            bucket[(d4.y << 6) + p1] = s4.y;
            int p2 = atomicAdd(&cnt[d4.z], 1);
            bucket[(d4.z << 6) + p2] = s4.z;
            int p3 = atomicAdd(&cnt[d4.w], 1);
            bucket[(d4.w << 6) + p3] = s4.w;
        }
        return;
    }

    __shared__ __align__(16) __bf16 w_lds[128 * 136];   // 34.8 KB

    for (int i = t; i < 4096; i += 512) {               // 8 iters
        float4 f = ((const float4*)W)[i];
        int n = i >> 5;
        int k = (i & 31) << 2;
        bf16x4 pk = { (__bf16)f.x, (__bf16)f.y, (__bf16)f.z, (__bf16)f.w };
        *(bf16x4*)&w_lds[n * 136 + k] = pk;             // ds_write_b64
    }
    __syncthreads();

    const int wave = t >> 6;           // 0..7
    const int lane = t & 63;
    const int q = lane >> 4;
    const int mr = lane & 15;

    const int m0 = blockIdx.x * 128 + wave * 16;
    int arow = m0 + mr;
    if (arow >= N_NODES) arow = N_NODES - 1;

    f32x4 acc[8] = {};

#pragma unroll
    for (int ks = 0; ks < 4; ++ks) {
        const int k0 = ks * 32 + q * 8;
        const float4* ap = (const float4*)&A_f32[(size_t)arow * DIM + k0];
        float4 a0 = ap[0], a1 = ap[1];
        bf16x8 af;
        af[0] = (__bf16)a0.x; af[1] = (__bf16)a0.y;
        af[2] = (__bf16)a0.z; af[3] = (__bf16)a0.w;
        af[4] = (__bf16)a1.x; af[5] = (__bf16)a1.y;
        af[6] = (__bf16)a1.z; af[7] = (__bf16)a1.w;
#pragma unroll
        for (int nt = 0; nt < 8; ++nt) {
            bf16x8 bfr = *(const bf16x8*)&w_lds[(nt * 16 + mr) * 136 + k0];
            acc[nt] = __builtin_amdgcn_mfma_f32_16x16x32_bf16(af, bfr, acc[nt], 0, 0, 0);
        }
    }

    __syncthreads();                   // all w_lds reads done
    float* lds_f = (float*)w_lds;      // 64 x 132 fp32 buffer (33.8 KB)
    const int nb = blockIdx.x * 128;

#pragma unroll
    for (int half = 0; half < 2; ++half) {
        if ((wave >> 2) == half) {
            int lw = wave & 3;
#pragma unroll
            for (int nt = 0; nt < 8; ++nt)
#pragma unroll
                for (int r = 0; r < 4; ++r)
                    lds_f[(lw * 16 + q * 4 + r) * 132 + nt * 16 + mr] = acc[nt][r];
        }
        __syncthreads();
        for (int i = t; i < 2048; i += 512) {
            int lr = i >> 5;
            int cg = (i & 31) << 2;
            int grow = nb + half * 64 + lr;
            if (grow < N_NODES) {
                float4 v = *(const float4*)&lds_f[lr * 132 + cg];
                float4 b4 = *(const float4*)&bias[cg];
                bf16x4 o;
                o[0] = (__bf16)fmaxf(v.x + b4.x, 0.f);
                o[1] = (__bf16)fmaxf(v.y + b4.y, 0.f);
                o[2] = (__bf16)fmaxf(v.z + b4.z, 0.f);
                o[3] = (__bf16)fmaxf(v.w + b4.w, 0.f);
                *(bf16x4*)&out_bf16[(size_t)grow * DIM + cg] = o;
            }
        }
        __syncthreads();
    }
}

// ===========================================================================
// K2: aggregate + GIN combine (unchanged from R9 — max-TLP, one wave/node).
// Writes c = bf16(1 + eps*h_self + sum_neigh h).
// ===========================================================================
__global__ __launch_bounds__(256) void agg_combine_k(
    const __bf16* __restrict__ h,
    const int* __restrict__ cnt,
    const int* __restrict__ bucket,
    const float* __restrict__ eps_p,
    __bf16* __restrict__ c)
{
    const int t = threadIdx.x;
    const int node = blockIdx.x * 4 + (t >> 6);
    const int lane = t & 63;
    const int ch = lane << 1;

    const int deg = cnt[node];
    const int base = node << 6;
    const int ZROW = N_NODES;

    float ax = 0.f, ay = 0.f;
    for (int e = 0; e < deg; e += 4) {
        uint4 i4 = *(const uint4*)&bucket[base + e];
        int s0 = (int)i4.x;
        int s1 = (e + 1 < deg) ? (int)i4.y : ZROW;
        int s2 = (e + 2 < deg) ? (int)i4.z : ZROW;
        int s3 = (e + 3 < deg) ? (int)i4.w : ZROW;
        unsigned v0 = *(const unsigned*)&h[(size_t)s0 * DIM + ch];
        unsigned v1 = *(const unsigned*)&h[(size_t)s1 * DIM + ch];
        unsigned v2 = *(const unsigned*)&h[(size_t)s2 * DIM + ch];
        unsigned v3 = *(const unsigned*)&h[(size_t)s3 * DIM + ch];
        ax += bflo(v0) + bflo(v1) + bflo(v2) + bflo(v3);
        ay += bfhi(v0) + bfhi(v1) + bfhi(v2) + bfhi(v3);
    }

    const float eps = eps_p[0];
    unsigned sv = *(const unsigned*)&h[(size_t)node * DIM + ch];
    bf16x2 o;
    o[0] = (__bf16)(1.0f + eps * bflo(sv) + ax);
    o[1] = (__bf16)(1.0f + eps * bfhi(sv) + ay);
    *(bf16x2*)&c[(size_t)node * DIM + ch] = o;
}

// ===========================================================================
// K3: pure bf16 MFMA GEMM + bias + relu, 512-thread / 128-row blocks.
// ===========================================================================
__global__ __launch_bounds__(512) void gemm2_k(
    const __bf16* __restrict__ A,
    const float* __restrict__ W,
    const float* __restrict__ bias,
    float* __restrict__ out)
{
    __shared__ __align__(16) __bf16 w_lds[128 * 136];   // 34.8 KB

    const int t = threadIdx.x;

    for (int i = t; i < 4096; i += 512) {
        float4 f = ((const float4*)W)[i];
        int n = i >> 5;
        int k = (i & 31) << 2;
        bf16x4 pk = { (__bf16)f.x, (__bf16)f.y, (__bf16)f.z, (__bf16)f.w };
        *(bf16x4*)&w_lds[n * 136 + k] = pk;
    }
    __syncthreads();

    const int wave = t >> 6;
    const int lane = t & 63;
    const int q = lane >> 4;
    const int mr = lane & 15;

    const int m0 = blockIdx.x * 128 + wave * 16;
    int arow = m0 + mr;
    if (arow >= N_NODES) arow = N_NODES - 1;

    f32x4 acc[8] = {};

#pragma unroll
    for (int ks = 0; ks < 4; ++ks) {
        const int k0 = ks * 32 + q * 8;
        bf16x8 af = *(const bf16x8*)&A[(size_t)arow * DIM + k0];
#pragma unroll
        for (int nt = 0; nt < 8; ++nt) {
            bf16x8 bfr = *(const bf16x8*)&w_lds[(nt * 16 + mr) * 136 + k0];
            acc[nt] = __builtin_amdgcn_mfma_f32_16x16x32_bf16(af, bfr, acc[nt], 0, 0, 0);
        }
    }

    __syncthreads();
    float* lds_f = (float*)w_lds;      // 64 x 132 fp32
    const int nb = blockIdx.x * 128;

#pragma unroll
    for (int half = 0; half < 2; ++half) {
        if ((wave >> 2) == half) {
            int lw = wave & 3;
#pragma unroll
            for (int nt = 0; nt < 8; ++nt)
#pragma unroll
                for (int r = 0; r < 4; ++r)
                    lds_f[(lw * 16 + q * 4 + r) * 132 + nt * 16 + mr] = acc[nt][r];
        }
        __syncthreads();
        for (int i = t; i < 2048; i += 512) {
            int lr = i >> 5;
            int cg = (i & 31) << 2;
            int grow = nb + half * 64 + lr;
            if (grow < N_NODES) {
                float4 v = *(const float4*)&lds_f[lr * 132 + cg];
                float4 b4 = *(const float4*)&bias[cg];
                v.x = fmaxf(v.x + b4.x, 0.f);
                v.y = fmaxf(v.y + b4.y, 0.f);
                v.z = fmaxf(v.z + b4.z, 0.f);
                v.w = fmaxf(v.w + b4.w, 0.f);
                *(float4*)&out[(size_t)grow * DIM + cg] = v;
            }
        }
        __syncthreads();
    }
}

extern "C" void kernel_launch(void* const* d_in, const int* in_sizes, int n_in,
                              void* d_out, int out_size, void* d_ws, size_t ws_size,
                              hipStream_t stream) {
    const float* feats = (const float*)d_in[0];
    const int*   src   = (const int*)d_in[1];
    const int*   dst   = (const int*)d_in[2];
    const float* W_f   = (const float*)d_in[3];
    const float* b_f   = (const float*)d_in[4];
    const float* W_phy = (const float*)d_in[5];
    const float* b_phy = (const float*)d_in[6];
    const float* eps   = (const float*)d_in[7];
    float* out = (float*)d_out;

    const size_t HN = (size_t)(N_NODES + 1) * DIM;      // +1 zero row
    __bf16* h   = (__bf16*)d_ws;                        // 12.8 MB
    __bf16* c   = h + HN;                               // 12.8 MB
    int* bucket = (int*)(c + (size_t)N_NODES * DIM);    // 12.8 MB
    int* cnt    = bucket + (size_t)N_NODES * CAP;       // 200 KB

    const int gblocks = (N_NODES + 127) / 128;          // 391
    const int fblocks = (N_EDGES / 4 + 511) / 512;      // 306

    hipMemsetAsync(cnt, 0, N_NODES * sizeof(int), stream);

    gemm1_fill_k<<<gblocks + fblocks, 512, 0, stream>>>(
        feats, W_f, b_f, h, src, dst, cnt, bucket, gblocks);

    agg_combine_k<<<N_NODES / 4, 256, 0, stream>>>(
        h, cnt, bucket, eps, c);

    gemm2_k<<<gblocks, 512, 0, stream>>>(
        c, W_phy, b_phy, out);
}